// Round 1
// baseline (146.480 us; speedup 1.0000x reference)
//
#include <hip/hip_runtime.h>
#include <math.h>

#define Bb 4
#define Cc 32
#define Nn 200
#define Tt 2048
#define Ss 24
#define EPSf 1e-5f

typedef float f4 __attribute__((ext_vector_type(4)));
typedef int i4 __attribute__((ext_vector_type(4)));

// ws layout (floats): [0,768) gsum, [768,1536) gsq, [1536,2304) mean, [2304,3072) rstd

__global__ __launch_bounds__(256) void k_init(float* __restrict__ ws) {
    int i = blockIdx.x * 256 + threadIdx.x;
    if (i < 2 * Ss * Cc) ws[i] = 0.0f;
}

__global__ __launch_bounds__(256) void k_partial(const float* __restrict__ x,
                                                 const int* __restrict__ timei,
                                                 float* __restrict__ gsum,
                                                 float* __restrict__ gsq) {
    __shared__ float lsum[Ss];
    __shared__ float lsq[Ss];
    const int tid = threadIdx.x;
    const int bx  = blockIdx.x;
    // grid = 2 (t-tiles) * 8 (n-chunks) * 128 (b*c) = 2048
    const int tt = bx & 1;
    const int nc = (bx >> 1) & 7;
    const int bc = bx >> 4;
    const int b  = bc >> 5;
    const int c  = bc & 31;

    if (tid < Ss) { lsum[tid] = 0.0f; lsq[tid] = 0.0f; }
    __syncthreads();

    const int t0 = tt * 1024 + tid * 4;
    const i4 sl = *(const i4*)(timei + b * Tt + t0);

    const float* base = x + ((size_t)((b * Cc + c) * Nn)) * Tt + t0;
    float s0 = 0.f, s1 = 0.f, s2 = 0.f, s3 = 0.f;
    float q0 = 0.f, q1 = 0.f, q2 = 0.f, q3 = 0.f;
    const int n0 = nc * 25;
#pragma unroll 5
    for (int n = n0; n < n0 + 25; ++n) {
        f4 v = *(const f4*)(base + (size_t)n * Tt);
        s0 += v[0]; q0 += v[0] * v[0];
        s1 += v[1]; q1 += v[1] * v[1];
        s2 += v[2]; q2 += v[2] * v[2];
        s3 += v[3]; q3 += v[3] * v[3];
    }
    atomicAdd(&lsum[sl[0]], s0); atomicAdd(&lsq[sl[0]], q0);
    atomicAdd(&lsum[sl[1]], s1); atomicAdd(&lsq[sl[1]], q1);
    atomicAdd(&lsum[sl[2]], s2); atomicAdd(&lsq[sl[2]], q2);
    atomicAdd(&lsum[sl[3]], s3); atomicAdd(&lsq[sl[3]], q3);
    __syncthreads();

    if (tid < Ss) {
        atomicAdd(&gsum[tid * Cc + c], lsum[tid]);
        atomicAdd(&gsq[tid * Cc + c], lsq[tid]);
    }
}

__global__ __launch_bounds__(768) void k_finalize(const int* __restrict__ timei,
                                                  const float* __restrict__ gsum,
                                                  const float* __restrict__ gsq,
                                                  float* __restrict__ mean,
                                                  float* __restrict__ rstd) {
    __shared__ int hist[Ss];
    const int tid = threadIdx.x;
    if (tid < Ss) hist[tid] = 0;
    __syncthreads();
    for (int i = tid; i < Bb * Tt; i += 768) atomicAdd(&hist[timei[i]], 1);
    __syncthreads();
    if (tid < Ss * Cc) {
        const int s = tid >> 5;  // Cc == 32
        float cnt = (float)hist[s];
        float denom = fmaxf(cnt, 1e-12f) * (float)Nn;
        float m  = gsum[tid] / denom;
        float m2 = gsq[tid] / denom;
        float var = m2 - m * m;
        mean[tid] = m;
        rstd[tid] = 1.0f / sqrtf(var + EPSf);
    }
}

__global__ __launch_bounds__(256) void k_norm(const float* __restrict__ x,
                                              const int* __restrict__ timei,
                                              const float* __restrict__ mean,
                                              const float* __restrict__ rstd,
                                              float* __restrict__ out) {
    __shared__ float mt[Tt];
    __shared__ float rt[Tt];
    const int tid = threadIdx.x;
    const int bx  = blockIdx.x;
    // grid = 25 (n-chunks of 8) * 32 (c) * 4 (b) = 3200
    const int nchunk = bx % 25;
    const int c = (bx / 25) & 31;
    const int b = bx / (25 * 32);

    for (int t = tid; t < Tt; t += 256) {
        const int s = timei[b * Tt + t];
        mt[t] = mean[s * Cc + c];
        rt[t] = rstd[s * Cc + c];
    }
    __syncthreads();

    const size_t plane = (size_t)(b * Cc + c) * Nn;
    const int nbeg = nchunk * 8;
#pragma unroll
    for (int n = nbeg; n < nbeg + 8; ++n) {
        const float* xr = x + (plane + n) * Tt;
        float* orow = out + (plane + n) * Tt;
        for (int t4 = tid * 4; t4 < Tt; t4 += 1024) {
            f4 v = *(const f4*)(xr + t4);
            f4 m = *(const f4*)(&mt[t4]);
            f4 r = *(const f4*)(&rt[t4]);
            f4 o;
            o[0] = (v[0] - m[0]) * r[0];
            o[1] = (v[1] - m[1]) * r[1];
            o[2] = (v[2] - m[2]) * r[2];
            o[3] = (v[3] - m[3]) * r[3];
            *(f4*)(orow + t4) = o;
        }
    }
}

extern "C" void kernel_launch(void* const* d_in, const int* in_sizes, int n_in,
                              void* d_out, int out_size, void* d_ws, size_t ws_size,
                              hipStream_t stream) {
    const float* x    = (const float*)d_in[0];
    const int* timei  = (const int*)d_in[1];
    float* out = (float*)d_out;
    float* ws  = (float*)d_ws;
    float* gsum = ws;
    float* gsq  = ws + Ss * Cc;
    float* mean = ws + 2 * Ss * Cc;
    float* rstd = ws + 3 * Ss * Cc;

    k_init<<<6, 256, 0, stream>>>(ws);
    k_partial<<<2048, 256, 0, stream>>>(x, timei, gsum, gsq);
    k_finalize<<<1, 768, 0, stream>>>(timei, gsum, gsq, mean, rstd);
    k_norm<<<3200, 256, 0, stream>>>(x, timei, mean, rstd, out);
}

// Round 2
// 120.325 us; speedup vs baseline: 1.2174x; 1.2174x over previous
//
#include <hip/hip_runtime.h>
#include <math.h>

#define Bb 4
#define Cc 32
#define Nn 200
#define Tt 2048
#define Ss 24
#define EPSf 1e-5f

typedef float f4 __attribute__((ext_vector_type(4)));
typedef int i4 __attribute__((ext_vector_type(4)));

// ws layout (floats): [0,768) gsum, [768,1536) gsq, [1536,1560) hist (as int)

// Single small block: zero accumulators + histogram of time slots.
__global__ __launch_bounds__(1024) void k_prep(const int* __restrict__ timei,
                                               float* __restrict__ gss,
                                               int* __restrict__ hist) {
    __shared__ int lh[Ss];
    const int tid = threadIdx.x;
    if (tid < Ss) lh[tid] = 0;
    for (int i = tid; i < 2 * Ss * Cc; i += 1024) gss[i] = 0.0f;
    __syncthreads();
    for (int i = tid; i < Bb * Tt; i += 1024) atomicAdd(&lh[timei[i]], 1);
    __syncthreads();
    if (tid < Ss) hist[tid] = lh[tid];
}

__global__ __launch_bounds__(256) void k_partial(const float* __restrict__ x,
                                                 const int* __restrict__ timei,
                                                 float* __restrict__ gsum,
                                                 float* __restrict__ gsq) {
    __shared__ float lsum[Ss];
    __shared__ float lsq[Ss];
    const int tid = threadIdx.x;
    const int bx  = blockIdx.x;
    // grid = 2 (t-tiles) * 8 (n-chunks) * 128 (b*c) = 2048
    const int tt = bx & 1;
    const int nc = (bx >> 1) & 7;
    const int bc = bx >> 4;
    const int b  = bc >> 5;
    const int c  = bc & 31;

    if (tid < Ss) { lsum[tid] = 0.0f; lsq[tid] = 0.0f; }
    __syncthreads();

    const int t0 = tt * 1024 + tid * 4;
    const i4 sl = *(const i4*)(timei + b * Tt + t0);

    const float* base = x + ((size_t)((b * Cc + c) * Nn)) * Tt + t0;
    float s0 = 0.f, s1 = 0.f, s2 = 0.f, s3 = 0.f;
    float q0 = 0.f, q1 = 0.f, q2 = 0.f, q3 = 0.f;
    const int n0 = nc * 25;
#pragma unroll 5
    for (int n = n0; n < n0 + 25; ++n) {
        f4 v = *(const f4*)(base + (size_t)n * Tt);
        s0 += v[0]; q0 += v[0] * v[0];
        s1 += v[1]; q1 += v[1] * v[1];
        s2 += v[2]; q2 += v[2] * v[2];
        s3 += v[3]; q3 += v[3] * v[3];
    }
    atomicAdd(&lsum[sl[0]], s0); atomicAdd(&lsq[sl[0]], q0);
    atomicAdd(&lsum[sl[1]], s1); atomicAdd(&lsq[sl[1]], q1);
    atomicAdd(&lsum[sl[2]], s2); atomicAdd(&lsq[sl[2]], q2);
    atomicAdd(&lsum[sl[3]], s3); atomicAdd(&lsq[sl[3]], q3);
    __syncthreads();

    if (tid < Ss) {
        atomicAdd(&gsum[tid * Cc + c], lsum[tid]);
        atomicAdd(&gsq[tid * Cc + c], lsq[tid]);
    }
}

__global__ __launch_bounds__(256) void k_norm(const float* __restrict__ x,
                                              const int* __restrict__ timei,
                                              const float* __restrict__ gsum,
                                              const float* __restrict__ gsq,
                                              const int* __restrict__ hist,
                                              float* __restrict__ out) {
    __shared__ float sm[Ss];
    __shared__ float sr[Ss];
    __shared__ float mt[Tt];
    __shared__ float rt[Tt];
    const int tid = threadIdx.x;
    // Reverse order vs k_partial's streaming order: read MRU x regions first
    // so L3 evictions (from out writes, if nt doesn't bypass) hit the regions
    // we read last.
    const int idx = (Bb * Cc * 25 - 1) - blockIdx.x;
    const int nchunk = idx % 25;
    const int c = (idx / 25) & 31;
    const int b = idx / (25 * 32);

    if (tid < Ss) {
        float cnt   = (float)hist[tid];
        float denom = fmaxf(cnt, 1e-12f) * (float)Nn;
        float m     = gsum[tid * Cc + c] / denom;
        float m2    = gsq[tid * Cc + c] / denom;
        sm[tid] = m;
        sr[tid] = 1.0f / sqrtf(m2 - m * m + EPSf);
    }
    __syncthreads();

    for (int t = tid; t < Tt; t += 256) {
        const int s = timei[b * Tt + t];
        mt[t] = sm[s];
        rt[t] = sr[s];
    }
    __syncthreads();

    const size_t plane = (size_t)(b * Cc + c) * Nn;
    const int nbeg = nchunk * 8;
#pragma unroll
    for (int n = nbeg; n < nbeg + 8; ++n) {
        const float* xr = x + (plane + n) * Tt;
        float* orow = out + (plane + n) * Tt;
        for (int t4 = tid * 4; t4 < Tt; t4 += 1024) {
            f4 v = *(const f4*)(xr + t4);
            f4 m = *(const f4*)(&mt[t4]);
            f4 r = *(const f4*)(&rt[t4]);
            f4 o;
            o[0] = (v[0] - m[0]) * r[0];
            o[1] = (v[1] - m[1]) * r[1];
            o[2] = (v[2] - m[2]) * r[2];
            o[3] = (v[3] - m[3]) * r[3];
            __builtin_nontemporal_store(o, (f4*)(orow + t4));
        }
    }
}

extern "C" void kernel_launch(void* const* d_in, const int* in_sizes, int n_in,
                              void* d_out, int out_size, void* d_ws, size_t ws_size,
                              hipStream_t stream) {
    const float* x   = (const float*)d_in[0];
    const int* timei = (const int*)d_in[1];
    float* out  = (float*)d_out;
    float* ws   = (float*)d_ws;
    float* gsum = ws;
    float* gsq  = ws + Ss * Cc;
    int*   hist = (int*)(ws + 2 * Ss * Cc);

    k_prep<<<1, 1024, 0, stream>>>(timei, ws, hist);
    k_partial<<<2048, 256, 0, stream>>>(x, timei, gsum, gsq);
    k_norm<<<Bb * Cc * 25, 256, 0, stream>>>(x, timei, gsum, gsq, hist, out);
}

// Round 4
// 111.481 us; speedup vs baseline: 1.3139x; 1.0793x over previous
//
#include <hip/hip_runtime.h>
#include <math.h>

#define Bb 4
#define Cc 32
#define Nn 200
#define Tt 2048
#define Ss 24
#define EPSf 1e-5f
#define ROWS 50   // rows per block
#define NCH 4     // row-chunks per (b,c) plane

typedef float f4 __attribute__((ext_vector_type(4)));
typedef int i4 __attribute__((ext_vector_type(4)));
typedef unsigned int u2 __attribute__((ext_vector_type(2)));

__device__ __forceinline__ unsigned rne_bf16(float f) {
    unsigned u = __float_as_uint(f);
    return (u + 0x7FFFu + ((u >> 16) & 1u)) >> 16;
}
__device__ __forceinline__ unsigned pack2(float a, float b) {
    return rne_bf16(a) | (rne_bf16(b) << 16);
}
__device__ __forceinline__ float lo16(unsigned u) { return __uint_as_float(u << 16); }
__device__ __forceinline__ float hi16(unsigned u) { return __uint_as_float(u & 0xFFFF0000u); }

// ws layout (USE16): ushort xb16[4*32*200*2048]  (100 MiB)
//                    float2 part[32][24][16]; int cntpart[4][24]
// fallback:          part/cntpart at ws start.

template <bool USE16>
__global__ __launch_bounds__(256) void k_partial(const float* __restrict__ x,
                                                 const int* __restrict__ timei,
                                                 unsigned short* __restrict__ xb16,
                                                 float2* __restrict__ part,
                                                 int* __restrict__ cntpart) {
    __shared__ float lsum[Ss], lsq[Ss];
    __shared__ int   lcnt[Ss];
    const int tid = threadIdx.x;
    const int bx  = blockIdx.x;
    const int b   = bx >> 7;
    const int c   = (bx >> 2) & 31;
    const int nc  = bx & 3;
    const bool do_hist = (c == 0 && nc == 0);

    if (tid < Ss) { lsum[tid] = 0.f; lsq[tid] = 0.f; lcnt[tid] = 0; }
    __syncthreads();

    const int t0 = tid * 4;
    const i4 sl0 = *(const i4*)(timei + b * Tt + t0);
    const i4 sl1 = *(const i4*)(timei + b * Tt + t0 + 1024);

    const size_t plane = ((size_t)(b * Cc + c) * Nn + (size_t)nc * ROWS) * Tt;
    const float* bp = x + plane + t0;
    unsigned short* wp = xb16 + plane + t0;

    float s0=0,s1=0,s2=0,s3=0,s4=0,s5=0,s6=0,s7=0;
    float q0=0,q1=0,q2=0,q3=0,q4=0,q5=0,q6=0,q7=0;

#pragma unroll 5
    for (int r = 0; r < ROWS; ++r) {
        f4 v0, v1;
        if constexpr (USE16) {
            v0 = __builtin_nontemporal_load((const f4*)(bp + (size_t)r * Tt));
            v1 = __builtin_nontemporal_load((const f4*)(bp + (size_t)r * Tt + 1024));
            u2 w0, w1;
            w0[0] = pack2(v0[0], v0[1]); w0[1] = pack2(v0[2], v0[3]);
            w1[0] = pack2(v1[0], v1[1]); w1[1] = pack2(v1[2], v1[3]);
            *(u2*)(wp + (size_t)r * Tt)        = w0;   // normal store: allocate in L3
            *(u2*)(wp + (size_t)r * Tt + 1024) = w1;
        } else {
            v0 = *(const f4*)(bp + (size_t)r * Tt);
            v1 = *(const f4*)(bp + (size_t)r * Tt + 1024);
        }
        s0 += v0[0]; q0 += v0[0]*v0[0];
        s1 += v0[1]; q1 += v0[1]*v0[1];
        s2 += v0[2]; q2 += v0[2]*v0[2];
        s3 += v0[3]; q3 += v0[3]*v0[3];
        s4 += v1[0]; q4 += v1[0]*v1[0];
        s5 += v1[1]; q5 += v1[1]*v1[1];
        s6 += v1[2]; q6 += v1[2]*v1[2];
        s7 += v1[3]; q7 += v1[3]*v1[3];
    }

    atomicAdd(&lsum[sl0[0]], s0); atomicAdd(&lsq[sl0[0]], q0);
    atomicAdd(&lsum[sl0[1]], s1); atomicAdd(&lsq[sl0[1]], q1);
    atomicAdd(&lsum[sl0[2]], s2); atomicAdd(&lsq[sl0[2]], q2);
    atomicAdd(&lsum[sl0[3]], s3); atomicAdd(&lsq[sl0[3]], q3);
    atomicAdd(&lsum[sl1[0]], s4); atomicAdd(&lsq[sl1[0]], q4);
    atomicAdd(&lsum[sl1[1]], s5); atomicAdd(&lsq[sl1[1]], q5);
    atomicAdd(&lsum[sl1[2]], s6); atomicAdd(&lsq[sl1[2]], q6);
    atomicAdd(&lsum[sl1[3]], s7); atomicAdd(&lsq[sl1[3]], q7);
    if (do_hist) {
        atomicAdd(&lcnt[sl0[0]], 1); atomicAdd(&lcnt[sl0[1]], 1);
        atomicAdd(&lcnt[sl0[2]], 1); atomicAdd(&lcnt[sl0[3]], 1);
        atomicAdd(&lcnt[sl1[0]], 1); atomicAdd(&lcnt[sl1[1]], 1);
        atomicAdd(&lcnt[sl1[2]], 1); atomicAdd(&lcnt[sl1[3]], 1);
    }
    __syncthreads();

    if (tid < Ss) {
        part[(c * Ss + tid) * 16 + (b * NCH + nc)] = make_float2(lsum[tid], lsq[tid]);
        if (do_hist) cntpart[b * Ss + tid] = lcnt[tid];
    }
}

template <bool USE16>
__global__ __launch_bounds__(256) void k_norm(const float* __restrict__ x,
                                              const unsigned short* __restrict__ xb16,
                                              const int* __restrict__ timei,
                                              const float2* __restrict__ part,
                                              const int* __restrict__ cntpart,
                                              float* __restrict__ out) {
    __shared__ float lsum[Ss], lsq[Ss];
    __shared__ float s_mr[Ss], s_r[Ss];
    const int tid = threadIdx.x;
    const int bx  = blockIdx.x;
    const int b   = bx >> 7;
    const int c   = (bx >> 2) & 31;
    const int nc  = bx & 3;

    if (tid < Ss) { lsum[tid] = 0.f; lsq[tid] = 0.f; }
    __syncthreads();
    if (tid < 192) {
        const int s = tid >> 3, j = tid & 7;
        float2 p0 = part[(c * Ss + s) * 16 + 2 * j];
        float2 p1 = part[(c * Ss + s) * 16 + 2 * j + 1];
        atomicAdd(&lsum[s], p0.x + p1.x);
        atomicAdd(&lsq[s],  p0.y + p1.y);
    }
    __syncthreads();
    if (tid < Ss) {
        float cnt = (float)(cntpart[tid] + cntpart[Ss + tid] +
                            cntpart[2 * Ss + tid] + cntpart[3 * Ss + tid]);
        float denom = fmaxf(cnt, 1e-12f) * (float)Nn;
        float m  = lsum[tid] / denom;
        float m2 = lsq[tid]  / denom;
        float rr = 1.0f / sqrtf(m2 - m * m + EPSf);
        s_r[tid]  = rr;
        s_mr[tid] = m * rr;
    }
    __syncthreads();

    const int t0 = tid * 4;
    const i4 sl0 = *(const i4*)(timei + b * Tt + t0);
    const i4 sl1 = *(const i4*)(timei + b * Tt + t0 + 1024);
    const float rr0 = s_r[sl0[0]], mr0 = s_mr[sl0[0]];
    const float rr1 = s_r[sl0[1]], mr1 = s_mr[sl0[1]];
    const float rr2 = s_r[sl0[2]], mr2 = s_mr[sl0[2]];
    const float rr3 = s_r[sl0[3]], mr3 = s_mr[sl0[3]];
    const float rr4 = s_r[sl1[0]], mr4 = s_mr[sl1[0]];
    const float rr5 = s_r[sl1[1]], mr5 = s_mr[sl1[1]];
    const float rr6 = s_r[sl1[2]], mr6 = s_mr[sl1[2]];
    const float rr7 = s_r[sl1[3]], mr7 = s_mr[sl1[3]];

    const size_t plane = ((size_t)(b * Cc + c) * Nn + (size_t)nc * ROWS) * Tt;
    const unsigned short* rp = xb16 + plane + t0;
    const float* xp = x + plane + t0;
    float* op = out + plane + t0;

#pragma unroll 5
    for (int r = 0; r < ROWS; ++r) {
        f4 o0, o1;
        if constexpr (USE16) {
            u2 a0 = *(const u2*)(rp + (size_t)r * Tt);
            u2 a1 = *(const u2*)(rp + (size_t)r * Tt + 1024);
            o0[0] = fmaf(lo16(a0[0]), rr0, -mr0);
            o0[1] = fmaf(hi16(a0[0]), rr1, -mr1);
            o0[2] = fmaf(lo16(a0[1]), rr2, -mr2);
            o0[3] = fmaf(hi16(a0[1]), rr3, -mr3);
            o1[0] = fmaf(lo16(a1[0]), rr4, -mr4);
            o1[1] = fmaf(hi16(a1[0]), rr5, -mr5);
            o1[2] = fmaf(lo16(a1[1]), rr6, -mr6);
            o1[3] = fmaf(hi16(a1[1]), rr7, -mr7);
        } else {
            f4 v0 = *(const f4*)(xp + (size_t)r * Tt);
            f4 v1 = *(const f4*)(xp + (size_t)r * Tt + 1024);
            o0[0] = fmaf(v0[0], rr0, -mr0);
            o0[1] = fmaf(v0[1], rr1, -mr1);
            o0[2] = fmaf(v0[2], rr2, -mr2);
            o0[3] = fmaf(v0[3], rr3, -mr3);
            o1[0] = fmaf(v1[0], rr4, -mr4);
            o1[1] = fmaf(v1[1], rr5, -mr5);
            o1[2] = fmaf(v1[2], rr6, -mr6);
            o1[3] = fmaf(v1[3], rr7, -mr7);
        }
        __builtin_nontemporal_store(o0, (f4*)(op + (size_t)r * Tt));
        __builtin_nontemporal_store(o1, (f4*)(op + (size_t)r * Tt + 1024));
    }
}

extern "C" void kernel_launch(void* const* d_in, const int* in_sizes, int n_in,
                              void* d_out, int out_size, void* d_ws, size_t ws_size,
                              hipStream_t stream) {
    const float* x   = (const float*)d_in[0];
    const int* timei = (const int*)d_in[1];
    float* out = (float*)d_out;

    const size_t nb16 = (size_t)Bb * Cc * Nn * Tt * sizeof(unsigned short); // 100 MiB
    const size_t npart = (size_t)Cc * Ss * 16 * sizeof(float2);
    const size_t ncnt  = (size_t)Bb * Ss * sizeof(int);

    if (ws_size >= nb16 + npart + ncnt) {
        unsigned short* xb16 = (unsigned short*)d_ws;
        float2* part = (float2*)((char*)d_ws + nb16);
        int* cnt = (int*)((char*)d_ws + nb16 + npart);
        k_partial<true><<<Bb * Cc * NCH, 256, 0, stream>>>(x, timei, xb16, part, cnt);
        k_norm<true><<<Bb * Cc * NCH, 256, 0, stream>>>(x, xb16, timei, part, cnt, out);
    } else {
        float2* part = (float2*)d_ws;
        int* cnt = (int*)((char*)d_ws + npart);
        k_partial<false><<<Bb * Cc * NCH, 256, 0, stream>>>(x, timei, nullptr, part, cnt);
        k_norm<false><<<Bb * Cc * NCH, 256, 0, stream>>>(x, nullptr, timei, part, cnt, out);
    }
}

// Round 5
// 111.461 us; speedup vs baseline: 1.3142x; 1.0002x over previous
//
#include <hip/hip_runtime.h>
#include <hip/hip_cooperative_groups.h>
#include <math.h>

namespace cg = cooperative_groups;

#define Bb 4
#define Cc 32
#define Nn 200
#define Tt 2048
#define Ss 24
#define EPSf 1e-5f

typedef float f4 __attribute__((ext_vector_type(4)));
typedef int i4 __attribute__((ext_vector_type(4)));
typedef unsigned int u2 __attribute__((ext_vector_type(2)));

__device__ __forceinline__ unsigned rne_bf16(float f) {
    unsigned u = __float_as_uint(f);
    return (u + 0x7FFFu + ((u >> 16) & 1u)) >> 16;
}
__device__ __forceinline__ unsigned pack2(float a, float b) {
    return rne_bf16(a) | (rne_bf16(b) << 16);
}
__device__ __forceinline__ float lo16(unsigned u) { return __uint_as_float(u << 16); }
__device__ __forceinline__ float hi16(unsigned u) { return __uint_as_float(u & 0xFFFF0000u); }

// ================= cooperative single-pass =================
// grid 256 = 4(b) * 32(c) * 2(n-half); block 512 threads; thread owns
// t0..t0+3 of 100 rows -> 400 elems -> 200 packed-bf16 VGPRs.
// ws: float2 part[32*24*8]; int cntpart[4*24]
__global__ __launch_bounds__(512, 2) void k_one(const float* __restrict__ x,
                                                const int* __restrict__ timei,
                                                float2* __restrict__ part,
                                                int* __restrict__ cntpart,
                                                float* __restrict__ out) {
    __shared__ float lsum[Ss], lsq[Ss];
    __shared__ int   lcnt[Ss];
    __shared__ float s_r[Ss], s_mr[Ss];

    const int tid = threadIdx.x;
    const int bx  = blockIdx.x;
    const int b   = bx >> 6;
    const int c   = (bx >> 1) & 31;
    const int nh  = bx & 1;
    const bool do_hist = (c == 0 && nh == 0);

    if (tid < Ss) { lsum[tid] = 0.f; lsq[tid] = 0.f; lcnt[tid] = 0; }
    __syncthreads();

    const int t0 = tid * 4;
    const size_t plane = ((size_t)(b * Cc + c) * Nn + (size_t)nh * 100) * Tt;
    const float* bp = x + plane + t0;

    unsigned xb[200];
    float s0 = 0.f, s1 = 0.f, s2 = 0.f, s3 = 0.f;
    float q0 = 0.f, q1 = 0.f, q2 = 0.f, q3 = 0.f;

#pragma unroll
    for (int r = 0; r < 100; ++r) {
        f4 v = *(const f4*)(bp + (size_t)r * Tt);   // normal load: allocate in L3
        xb[2 * r]     = pack2(v[0], v[1]);
        xb[2 * r + 1] = pack2(v[2], v[3]);
        s0 += v[0]; q0 += v[0] * v[0];
        s1 += v[1]; q1 += v[1] * v[1];
        s2 += v[2]; q2 += v[2] * v[2];
        s3 += v[3]; q3 += v[3] * v[3];
    }

    const i4 sl = *(const i4*)(timei + b * Tt + t0);
    atomicAdd(&lsum[sl[0]], s0); atomicAdd(&lsq[sl[0]], q0);
    atomicAdd(&lsum[sl[1]], s1); atomicAdd(&lsq[sl[1]], q1);
    atomicAdd(&lsum[sl[2]], s2); atomicAdd(&lsq[sl[2]], q2);
    atomicAdd(&lsum[sl[3]], s3); atomicAdd(&lsq[sl[3]], q3);
    if (do_hist) {
        atomicAdd(&lcnt[sl[0]], 1); atomicAdd(&lcnt[sl[1]], 1);
        atomicAdd(&lcnt[sl[2]], 1); atomicAdd(&lcnt[sl[3]], 1);
    }
    __syncthreads();

    if (tid < Ss) {
        part[(c * Ss + tid) * 8 + (b * 2 + nh)] = make_float2(lsum[tid], lsq[tid]);
        if (do_hist) cntpart[b * Ss + tid] = lcnt[tid];
    }

    cg::this_grid().sync();

    if (tid < Ss) { lsum[tid] = 0.f; lsq[tid] = 0.f; }
    __syncthreads();
    if (tid < 192) {
        const int s = tid >> 3, j = tid & 7;
        float2 p = part[(c * Ss + s) * 8 + j];
        atomicAdd(&lsum[s], p.x);
        atomicAdd(&lsq[s],  p.y);
    }
    __syncthreads();
    if (tid < Ss) {
        float cnt = (float)(cntpart[tid] + cntpart[Ss + tid] +
                            cntpart[2 * Ss + tid] + cntpart[3 * Ss + tid]);
        float denom = fmaxf(cnt, 1e-12f) * (float)Nn;
        float m  = lsum[tid] / denom;
        float m2 = lsq[tid]  / denom;
        float rr = 1.0f / sqrtf(m2 - m * m + EPSf);
        s_r[tid]  = rr;
        s_mr[tid] = m * rr;
    }
    __syncthreads();

    const float rr0 = s_r[sl[0]], mr0 = s_mr[sl[0]];
    const float rr1 = s_r[sl[1]], mr1 = s_mr[sl[1]];
    const float rr2 = s_r[sl[2]], mr2 = s_mr[sl[2]];
    const float rr3 = s_r[sl[3]], mr3 = s_mr[sl[3]];

    float* op = out + plane + t0;
#pragma unroll
    for (int r = 0; r < 100; ++r) {
        f4 o;
        o[0] = fmaf(lo16(xb[2 * r]),     rr0, -mr0);
        o[1] = fmaf(hi16(xb[2 * r]),     rr1, -mr1);
        o[2] = fmaf(lo16(xb[2 * r + 1]), rr2, -mr2);
        o[3] = fmaf(hi16(xb[2 * r + 1]), rr3, -mr3);
        __builtin_nontemporal_store(o, (f4*)(op + (size_t)r * Tt));
    }
}

// ================= fallback: round-4 two-pass =================
#define ROWS 50
#define NCH 4

template <bool USE16>
__global__ __launch_bounds__(256) void k_partial(const float* __restrict__ x,
                                                 const int* __restrict__ timei,
                                                 unsigned short* __restrict__ xb16,
                                                 float2* __restrict__ part,
                                                 int* __restrict__ cntpart) {
    __shared__ float lsum[Ss], lsq[Ss];
    __shared__ int   lcnt[Ss];
    const int tid = threadIdx.x;
    const int bx  = blockIdx.x;
    const int b   = bx >> 7;
    const int c   = (bx >> 2) & 31;
    const int nc  = bx & 3;
    const bool do_hist = (c == 0 && nc == 0);

    if (tid < Ss) { lsum[tid] = 0.f; lsq[tid] = 0.f; lcnt[tid] = 0; }
    __syncthreads();

    const int t0 = tid * 4;
    const i4 sl0 = *(const i4*)(timei + b * Tt + t0);
    const i4 sl1 = *(const i4*)(timei + b * Tt + t0 + 1024);

    const size_t plane = ((size_t)(b * Cc + c) * Nn + (size_t)nc * ROWS) * Tt;
    const float* bp = x + plane + t0;
    unsigned short* wp = xb16 + plane + t0;

    float s0=0,s1=0,s2=0,s3=0,s4=0,s5=0,s6=0,s7=0;
    float q0=0,q1=0,q2=0,q3=0,q4=0,q5=0,q6=0,q7=0;

#pragma unroll 5
    for (int r = 0; r < ROWS; ++r) {
        f4 v0, v1;
        if constexpr (USE16) {
            v0 = __builtin_nontemporal_load((const f4*)(bp + (size_t)r * Tt));
            v1 = __builtin_nontemporal_load((const f4*)(bp + (size_t)r * Tt + 1024));
            u2 w0, w1;
            w0[0] = pack2(v0[0], v0[1]); w0[1] = pack2(v0[2], v0[3]);
            w1[0] = pack2(v1[0], v1[1]); w1[1] = pack2(v1[2], v1[3]);
            *(u2*)(wp + (size_t)r * Tt)        = w0;
            *(u2*)(wp + (size_t)r * Tt + 1024) = w1;
        } else {
            v0 = *(const f4*)(bp + (size_t)r * Tt);
            v1 = *(const f4*)(bp + (size_t)r * Tt + 1024);
        }
        s0 += v0[0]; q0 += v0[0]*v0[0];
        s1 += v0[1]; q1 += v0[1]*v0[1];
        s2 += v0[2]; q2 += v0[2]*v0[2];
        s3 += v0[3]; q3 += v0[3]*v0[3];
        s4 += v1[0]; q4 += v1[0]*v1[0];
        s5 += v1[1]; q5 += v1[1]*v1[1];
        s6 += v1[2]; q6 += v1[2]*v1[2];
        s7 += v1[3]; q7 += v1[3]*v1[3];
    }

    atomicAdd(&lsum[sl0[0]], s0); atomicAdd(&lsq[sl0[0]], q0);
    atomicAdd(&lsum[sl0[1]], s1); atomicAdd(&lsq[sl0[1]], q1);
    atomicAdd(&lsum[sl0[2]], s2); atomicAdd(&lsq[sl0[2]], q2);
    atomicAdd(&lsum[sl0[3]], s3); atomicAdd(&lsq[sl0[3]], q3);
    atomicAdd(&lsum[sl1[0]], s4); atomicAdd(&lsq[sl1[0]], q4);
    atomicAdd(&lsum[sl1[1]], s5); atomicAdd(&lsq[sl1[1]], q5);
    atomicAdd(&lsum[sl1[2]], s6); atomicAdd(&lsq[sl1[2]], q6);
    atomicAdd(&lsum[sl1[3]], s7); atomicAdd(&lsq[sl1[3]], q7);
    if (do_hist) {
        atomicAdd(&lcnt[sl0[0]], 1); atomicAdd(&lcnt[sl0[1]], 1);
        atomicAdd(&lcnt[sl0[2]], 1); atomicAdd(&lcnt[sl0[3]], 1);
        atomicAdd(&lcnt[sl1[0]], 1); atomicAdd(&lcnt[sl1[1]], 1);
        atomicAdd(&lcnt[sl1[2]], 1); atomicAdd(&lcnt[sl1[3]], 1);
    }
    __syncthreads();

    if (tid < Ss) {
        part[(c * Ss + tid) * 16 + (b * NCH + nc)] = make_float2(lsum[tid], lsq[tid]);
        if (do_hist) cntpart[b * Ss + tid] = lcnt[tid];
    }
}

template <bool USE16>
__global__ __launch_bounds__(256) void k_norm(const float* __restrict__ x,
                                              const unsigned short* __restrict__ xb16,
                                              const int* __restrict__ timei,
                                              const float2* __restrict__ part,
                                              const int* __restrict__ cntpart,
                                              float* __restrict__ out) {
    __shared__ float lsum[Ss], lsq[Ss];
    __shared__ float s_mr[Ss], s_r[Ss];
    const int tid = threadIdx.x;
    const int bx  = blockIdx.x;
    const int b   = bx >> 7;
    const int c   = (bx >> 2) & 31;
    const int nc  = bx & 3;

    if (tid < Ss) { lsum[tid] = 0.f; lsq[tid] = 0.f; }
    __syncthreads();
    if (tid < 192) {
        const int s = tid >> 3, j = tid & 7;
        float2 p0 = part[(c * Ss + s) * 16 + 2 * j];
        float2 p1 = part[(c * Ss + s) * 16 + 2 * j + 1];
        atomicAdd(&lsum[s], p0.x + p1.x);
        atomicAdd(&lsq[s],  p0.y + p1.y);
    }
    __syncthreads();
    if (tid < Ss) {
        float cnt = (float)(cntpart[tid] + cntpart[Ss + tid] +
                            cntpart[2 * Ss + tid] + cntpart[3 * Ss + tid]);
        float denom = fmaxf(cnt, 1e-12f) * (float)Nn;
        float m  = lsum[tid] / denom;
        float m2 = lsq[tid]  / denom;
        float rr = 1.0f / sqrtf(m2 - m * m + EPSf);
        s_r[tid]  = rr;
        s_mr[tid] = m * rr;
    }
    __syncthreads();

    const int t0 = tid * 4;
    const i4 sl0 = *(const i4*)(timei + b * Tt + t0);
    const i4 sl1 = *(const i4*)(timei + b * Tt + t0 + 1024);
    const float rr0 = s_r[sl0[0]], mr0 = s_mr[sl0[0]];
    const float rr1 = s_r[sl0[1]], mr1 = s_mr[sl0[1]];
    const float rr2 = s_r[sl0[2]], mr2 = s_mr[sl0[2]];
    const float rr3 = s_r[sl0[3]], mr3 = s_mr[sl0[3]];
    const float rr4 = s_r[sl1[0]], mr4 = s_mr[sl1[0]];
    const float rr5 = s_r[sl1[1]], mr5 = s_mr[sl1[1]];
    const float rr6 = s_r[sl1[2]], mr6 = s_mr[sl1[2]];
    const float rr7 = s_r[sl1[3]], mr7 = s_mr[sl1[3]];

    const size_t plane = ((size_t)(b * Cc + c) * Nn + (size_t)nc * ROWS) * Tt;
    const unsigned short* rp = xb16 + plane + t0;
    const float* xp = x + plane + t0;
    float* op = out + plane + t0;

#pragma unroll 5
    for (int r = 0; r < ROWS; ++r) {
        f4 o0, o1;
        if constexpr (USE16) {
            u2 a0 = *(const u2*)(rp + (size_t)r * Tt);
            u2 a1 = *(const u2*)(rp + (size_t)r * Tt + 1024);
            o0[0] = fmaf(lo16(a0[0]), rr0, -mr0);
            o0[1] = fmaf(hi16(a0[0]), rr1, -mr1);
            o0[2] = fmaf(lo16(a0[1]), rr2, -mr2);
            o0[3] = fmaf(hi16(a0[1]), rr3, -mr3);
            o1[0] = fmaf(lo16(a1[0]), rr4, -mr4);
            o1[1] = fmaf(hi16(a1[0]), rr5, -mr5);
            o1[2] = fmaf(lo16(a1[1]), rr6, -mr6);
            o1[3] = fmaf(hi16(a1[1]), rr7, -mr7);
        } else {
            f4 v0 = *(const f4*)(xp + (size_t)r * Tt);
            f4 v1 = *(const f4*)(xp + (size_t)r * Tt + 1024);
            o0[0] = fmaf(v0[0], rr0, -mr0);
            o0[1] = fmaf(v0[1], rr1, -mr1);
            o0[2] = fmaf(v0[2], rr2, -mr2);
            o0[3] = fmaf(v0[3], rr3, -mr3);
            o1[0] = fmaf(v1[0], rr4, -mr4);
            o1[1] = fmaf(v1[1], rr5, -mr5);
            o1[2] = fmaf(v1[2], rr6, -mr6);
            o1[3] = fmaf(v1[3], rr7, -mr7);
        }
        __builtin_nontemporal_store(o0, (f4*)(op + (size_t)r * Tt));
        __builtin_nontemporal_store(o1, (f4*)(op + (size_t)r * Tt + 1024));
    }
}

extern "C" void kernel_launch(void* const* d_in, const int* in_sizes, int n_in,
                              void* d_out, int out_size, void* d_ws, size_t ws_size,
                              hipStream_t stream) {
    const float* x   = (const float*)d_in[0];
    const int* timei = (const int*)d_in[1];
    float* out = (float*)d_out;

    // ---- cooperative single-pass path ----
    {
        float2* part = (float2*)d_ws;                                 // 48 KiB
        int* cnt = (int*)((char*)d_ws + (size_t)Cc * Ss * 8 * sizeof(float2));
        int occ = 0;
        hipError_t q = hipOccupancyMaxActiveBlocksPerMultiprocessor(&occ, k_one, 512, 0);
        if (q == hipSuccess && occ >= 1) {
            void* args[] = { (void*)&x, (void*)&timei, (void*)&part, (void*)&cnt, (void*)&out };
            hipError_t rc = hipLaunchCooperativeKernel((const void*)k_one,
                                                       dim3(Bb * Cc * 2), dim3(512),
                                                       args, 0, stream);
            if (rc == hipSuccess) return;
            (void)hipGetLastError();  // clear sticky error, fall through
        } else {
            (void)hipGetLastError();
        }
    }

    // ---- fallback: two-pass ----
    const size_t nb16  = (size_t)Bb * Cc * Nn * Tt * sizeof(unsigned short); // 100 MiB
    const size_t npart = (size_t)Cc * Ss * 16 * sizeof(float2);
    const size_t ncnt  = (size_t)Bb * Ss * sizeof(int);

    if (ws_size >= nb16 + npart + ncnt) {
        unsigned short* xb16 = (unsigned short*)d_ws;
        float2* part = (float2*)((char*)d_ws + nb16);
        int* cnt = (int*)((char*)d_ws + nb16 + npart);
        k_partial<true><<<Bb * Cc * NCH, 256, 0, stream>>>(x, timei, xb16, part, cnt);
        k_norm<true><<<Bb * Cc * NCH, 256, 0, stream>>>(x, xb16, timei, part, cnt, out);
    } else {
        float2* part = (float2*)d_ws;
        int* cnt = (int*)((char*)d_ws + npart);
        k_partial<false><<<Bb * Cc * NCH, 256, 0, stream>>>(x, timei, nullptr, part, cnt);
        k_norm<false><<<Bb * Cc * NCH, 256, 0, stream>>>(x, nullptr, timei, part, cnt, out);
    }
}

// Round 6
// 104.235 us; speedup vs baseline: 1.4053x; 1.0693x over previous
//
#include <hip/hip_runtime.h>
#include <math.h>

#define Bb 4
#define Cc 32
#define Nn 200
#define Tt 2048
#define Ss 24
#define EPSf 1e-5f

typedef float f4 __attribute__((ext_vector_type(4)));
typedef int i4 __attribute__((ext_vector_type(4)));

// ws layout: float2 part[32][24][64]   (sum,sumsq per (c,slot,chunk))  384 KiB
//            int    cntpart[8][24]     (per (b,tt) histogram slice)    768 B
// Every slot is written unconditionally -> no zero-init kernel needed.

__global__ __launch_bounds__(256) void k_stats(const float* __restrict__ x,
                                               const int* __restrict__ timei,
                                               float2* __restrict__ part,
                                               int* __restrict__ cntpart) {
    __shared__ float lsum[Ss], lsq[Ss];
    __shared__ int   lcnt[Ss];
    const int tid = threadIdx.x;
    const int bx  = blockIdx.x;
    // grid = 2048: tt(2) x nc(8, 25-row chunks) x b(4) x c(32)
    const int tt = bx & 1;
    const int nc = (bx >> 1) & 7;
    const int bc = bx >> 4;
    const int b  = bc >> 5;
    const int c  = bc & 31;
    const bool do_hist = (c == 0 && nc == 0);

    if (tid < Ss) { lsum[tid] = 0.f; lsq[tid] = 0.f; lcnt[tid] = 0; }
    __syncthreads();

    const int t0 = tt * 1024 + tid * 4;
    const i4 sl = *(const i4*)(timei + b * Tt + t0);

    const size_t plane = ((size_t)(b * Cc + c) * Nn + (size_t)nc * 25) * Tt;
    const float* bp = x + plane + t0;

    float s0 = 0.f, s1 = 0.f, s2 = 0.f, s3 = 0.f;
    float q0 = 0.f, q1 = 0.f, q2 = 0.f, q3 = 0.f;
#pragma unroll 5
    for (int r = 0; r < 25; ++r) {
        f4 v = *(const f4*)(bp + (size_t)r * Tt);   // normal load: allocate in L3
        s0 += v[0]; q0 += v[0] * v[0];
        s1 += v[1]; q1 += v[1] * v[1];
        s2 += v[2]; q2 += v[2] * v[2];
        s3 += v[3]; q3 += v[3] * v[3];
    }

    atomicAdd(&lsum[sl[0]], s0); atomicAdd(&lsq[sl[0]], q0);
    atomicAdd(&lsum[sl[1]], s1); atomicAdd(&lsq[sl[1]], q1);
    atomicAdd(&lsum[sl[2]], s2); atomicAdd(&lsq[sl[2]], q2);
    atomicAdd(&lsum[sl[3]], s3); atomicAdd(&lsq[sl[3]], q3);
    if (do_hist) {
        atomicAdd(&lcnt[sl[0]], 1); atomicAdd(&lcnt[sl[1]], 1);
        atomicAdd(&lcnt[sl[2]], 1); atomicAdd(&lcnt[sl[3]], 1);
    }
    __syncthreads();

    const int chunk = (b * 2 + tt) * 8 + nc;   // [0,64)
    if (tid < Ss) {
        part[(c * Ss + tid) * 64 + chunk] = make_float2(lsum[tid], lsq[tid]);
        if (do_hist) cntpart[(b * 2 + tt) * Ss + tid] = lcnt[tid];
    }
}

__global__ __launch_bounds__(256) void k_norm(const float* __restrict__ x,
                                              const int* __restrict__ timei,
                                              const float2* __restrict__ part,
                                              const int* __restrict__ cntpart,
                                              float* __restrict__ out) {
    __shared__ float lsum[Ss], lsq[Ss];
    __shared__ float s_mr[Ss], s_r[Ss];
    const int tid = threadIdx.x;
    const int bx  = blockIdx.x;
    // grid = 512: b(4) x c(32) x nc(4, 50-row chunks)
    const int b  = bx >> 7;
    const int c  = (bx >> 2) & 31;
    const int nc = bx & 3;

    if (tid < Ss) { lsum[tid] = 0.f; lsq[tid] = 0.f; }
    __syncthreads();
    if (tid < 192) {                 // 24 slots x 8 groups of 8 chunks
        const int s = tid >> 3, j = tid & 7;
        const float2* pp = &part[(c * Ss + s) * 64 + j * 8];
        float ps = 0.f, pq = 0.f;
#pragma unroll
        for (int k = 0; k < 8; ++k) { ps += pp[k].x; pq += pp[k].y; }
        atomicAdd(&lsum[s], ps);
        atomicAdd(&lsq[s],  pq);
    }
    __syncthreads();
    if (tid < Ss) {
        int cnt = 0;
#pragma unroll
        for (int h = 0; h < 8; ++h) cnt += cntpart[h * Ss + tid];
        float denom = fmaxf((float)cnt, 1e-12f) * (float)Nn;
        float m  = lsum[tid] / denom;
        float m2 = lsq[tid]  / denom;
        float rr = 1.0f / sqrtf(m2 - m * m + EPSf);
        s_r[tid]  = rr;
        s_mr[tid] = m * rr;
    }
    __syncthreads();

    const int t0 = tid * 4;
    const i4 sl0 = *(const i4*)(timei + b * Tt + t0);
    const i4 sl1 = *(const i4*)(timei + b * Tt + t0 + 1024);
    const float rr0 = s_r[sl0[0]], mr0 = s_mr[sl0[0]];
    const float rr1 = s_r[sl0[1]], mr1 = s_mr[sl0[1]];
    const float rr2 = s_r[sl0[2]], mr2 = s_mr[sl0[2]];
    const float rr3 = s_r[sl0[3]], mr3 = s_mr[sl0[3]];
    const float rr4 = s_r[sl1[0]], mr4 = s_mr[sl1[0]];
    const float rr5 = s_r[sl1[1]], mr5 = s_mr[sl1[1]];
    const float rr6 = s_r[sl1[2]], mr6 = s_mr[sl1[2]];
    const float rr7 = s_r[sl1[3]], mr7 = s_mr[sl1[3]];

    const size_t plane = ((size_t)(b * Cc + c) * Nn + (size_t)nc * 50) * Tt;
    const float* xp = x + plane + t0;
    float* op = out + plane + t0;

#pragma unroll 5
    for (int r = 0; r < 50; ++r) {
        f4 v0 = *(const f4*)(xp + (size_t)r * Tt);           // L3-resident read
        f4 v1 = *(const f4*)(xp + (size_t)r * Tt + 1024);
        f4 o0, o1;
        o0[0] = fmaf(v0[0], rr0, -mr0);
        o0[1] = fmaf(v0[1], rr1, -mr1);
        o0[2] = fmaf(v0[2], rr2, -mr2);
        o0[3] = fmaf(v0[3], rr3, -mr3);
        o1[0] = fmaf(v1[0], rr4, -mr4);
        o1[1] = fmaf(v1[1], rr5, -mr5);
        o1[2] = fmaf(v1[2], rr6, -mr6);
        o1[3] = fmaf(v1[3], rr7, -mr7);
        __builtin_nontemporal_store(o0, (f4*)(op + (size_t)r * Tt));
        __builtin_nontemporal_store(o1, (f4*)(op + (size_t)r * Tt + 1024));
    }
}

extern "C" void kernel_launch(void* const* d_in, const int* in_sizes, int n_in,
                              void* d_out, int out_size, void* d_ws, size_t ws_size,
                              hipStream_t stream) {
    const float* x   = (const float*)d_in[0];
    const int* timei = (const int*)d_in[1];
    float* out = (float*)d_out;

    float2* part = (float2*)d_ws;                                  // 384 KiB
    int* cnt = (int*)((char*)d_ws + (size_t)Cc * Ss * 64 * sizeof(float2));

    k_stats<<<2048, 256, 0, stream>>>(x, timei, part, cnt);
    k_norm<<<512, 256, 0, stream>>>(x, timei, part, cnt, out);
}